// Round 6
// baseline (754.242 us; speedup 1.0000x reference)
//
#include <hip/hip_runtime.h>

// Fuzzy c-means on MI355X. N=300000, D=64, c=64, m=2 (p=2), 25 updates + init.
// R4: MFMA rewrite (432us). R5: bf16 xbf copy (427us). R6: VALU cuts (401us).
// R7: coalesced prep, nb=768 (390us). R8: per-wave-points GEMM1 (388us).
// R9: pipelined pass = WIN, atomic reduce = LOSS (470us). R10: R9 pass +
// R8 reduce (379us; pass ~8.8us warm, reduce ~3.5us, ~40us launch gaps).
// R11: fuse reduce INTO the next pass (fcm_iter): blocks 0-63 reduce prev
// partials -> C_new, all 768 blocks spin on device-scope rdone (co-residency
// GUARANTEED: launch_bounds(256,3) + LDS 46.7KB -> 3 blocks/CU = 768), tile-0
// prefetch issued before the wait. 54 -> 29 launches; kills per-iter gap +
// reduce-kernel ramp. rdone is monotonic (target 64*(k+1)) -> replay-safe.

#define DM 64
#define CL 64
#define PARTIAL_STRIDE 4160      // 64*64 num + 64 den
#define MAX_ITER 25
#define MAX_BLOCKS 768
#define LDP 72                   // padded row length (bf16) for Xb/XTb/umT

typedef __attribute__((ext_vector_type(8))) short bf16x8;   // MFMA A/B frag (4 VGPRs)
typedef __attribute__((ext_vector_type(4))) float f32x4;    // MFMA C/D frag

__device__ __forceinline__ unsigned f2bf1(float f) {        // fp32 -> bf16 (RNE)
  unsigned u = __builtin_bit_cast(unsigned, f);
  return (u + 0x7FFFu + ((u >> 16) & 1u)) >> 16;
}
__device__ __forceinline__ unsigned pkbf(float a, float b) {
  return f2bf1(a) | (f2bf1(b) << 16);
}
// HW packed fp32->2xbf16 (RNE), gfx950. %1 -> low half, %2 -> high half.
__device__ __forceinline__ unsigned cvtpk_bf16(float a, float b) {
  unsigned r;
  asm("v_cvt_pk_bf16_f32 %0, %1, %2" : "=v"(r) : "v"(a), "v"(b));
  return r;
}

// 64-lane sum: DPP row reduce + bcast, result broadcast via readlane 63.
__device__ __forceinline__ float wave_sum(float v) {
#define DPPADD(ctrl, rmask)                                                  \
  v += __builtin_bit_cast(float, __builtin_amdgcn_update_dpp(                \
           0, __builtin_bit_cast(int, v), ctrl, rmask, 0xf, false));
  DPPADD(0x111, 0xf)   // row_shr:1
  DPPADD(0x112, 0xf)   // row_shr:2
  DPPADD(0x114, 0xf)   // row_shr:4
  DPPADD(0x118, 0xf)   // row_shr:8
  DPPADD(0x142, 0xa)   // row_bcast:15
  DPPADD(0x143, 0xc)   // row_bcast:31
#undef DPPADD
  return __builtin_bit_cast(
      float, __builtin_amdgcn_readlane(__builtin_bit_cast(int, v), 63));
}

// all-lanes sum within each 16-lane group, pure VALU (DPP).
__device__ __forceinline__ float group16_sum(float v) {
#define DPPADD(ctrl)                                                         \
  v += __builtin_bit_cast(float, __builtin_amdgcn_update_dpp(                \
           0, __builtin_bit_cast(int, v), ctrl, 0xf, 0xf, false));
  DPPADD(0xB1)    // quad_perm [1,0,3,2]  (xor 1)
  DPPADD(0x4E)    // quad_perm [2,3,0,1]  (xor 2)
  DPPADD(0x141)   // row_half_mirror
  DPPADD(0x140)   // row_mirror
#undef DPPADD
  return v;
}

// Coalesced prep: one float4 per lane, 16 lanes = one data row.
__global__ __launch_bounds__(256)
void fcm_prep(const float* __restrict__ data, float* __restrict__ x2,
              unsigned short* __restrict__ xbf,
              float* __restrict__ diffac, int* __restrict__ done,
              int* __restrict__ ticket, int* __restrict__ rdone, int N) {
  size_t i = (size_t)blockIdx.x * blockDim.x + threadIdx.x;   // float4 index
  if (i == 0) { *diffac = 0.0f; *done = 0; *ticket = 0; *rdone = 0; }
  size_t nvec = (size_t)N * (DM / 4);
  if (i >= nvec) return;                 // rows are 16 vecs: groups all-in/all-out
  float4 v = ((const float4*)data)[i];
  float s = fmaf(v.x, v.x, fmaf(v.y, v.y, fmaf(v.z, v.z, v.w * v.w)));
  float rs = group16_sum(s);             // row sum across the 16-lane group
  if ((threadIdx.x & 15) == 0) x2[i >> 4] = rs;
  uint2 pk = {cvtpk_bf16(v.x, v.y), cvtpk_bf16(v.z, v.w)};
  ((uint2*)xbf)[i] = pk;
}

// INIT pass: W := u0 raw memberships; pipelined staging; writes partials.
__global__ __launch_bounds__(256, 3)
void fcm_pass_init(const unsigned short* __restrict__ xbf,
                   const float* __restrict__ CU,   // u0[N][64]
                   float* __restrict__ partial, int N, int ntiles) {
  __shared__ __align__(16) unsigned short Xb[2][64 * LDP];
  __shared__ __align__(16) unsigned short XTb[2][64 * LDP];
  __shared__ __align__(16) unsigned short umT[64 * LDP];

  const int tid  = threadIdx.x;
  const int w    = __builtin_amdgcn_readfirstlane(tid >> 6);
  const int col  = tid & 15;
  const int quad = (tid >> 4) & 3;

  union { bf16x8 v; unsigned u[4]; } ON;
  ON.u[0] = ON.u[1] = ON.u[2] = ON.u[3] = 0x3F803F80u;
  const bf16x8 onesf = ON.v;

  f32x4 D2[4];
#pragma unroll
  for (int dt = 0; dt < 4; dt++) D2[dt] = f32x4{0.f, 0.f, 0.f, 0.f};
  f32x4 Dden = f32x4{0.f, 0.f, 0.f, 0.f};

  const int sp  = tid & 63;
  const int sd0 = (tid >> 6) * 8;
  const unsigned short* gsrc = xbf + (size_t)sp * DM + sd0;

  auto do_gemm2 = [&](int cb) {
#pragma unroll
    for (int pb = 0; pb < 2; pb++) {
      bf16x8 au = *(const bf16x8*)(const void*)&umT[(16 * w + col) * LDP + pb * 32 + quad * 8];
      Dden = __builtin_amdgcn_mfma_f32_16x16x32_bf16(au, onesf, Dden, 0, 0, 0);
#pragma unroll
      for (int dt = 0; dt < 4; dt++) {
        bf16x8 bx = *(const bf16x8*)(const void*)&XTb[cb][(dt * 16 + col) * LDP + pb * 32 + quad * 8];
        D2[dt] = __builtin_amdgcn_mfma_f32_16x16x32_bf16(au, bx, D2[dt], 0, 0, 0);
      }
    }
  };

  bf16x8 rv0 = {0, 0, 0, 0, 0, 0, 0, 0};
  bf16x8 rv1 = {0, 0, 0, 0, 0, 0, 0, 0};
  {
    int t0 = blockIdx.x;
    if (t0 < ntiles) {
      int base = t0 * 64;
      int np = min(64, N - base);
      if (sp < np) {
        const unsigned short* g = gsrc + (size_t)base * DM;
        rv0 = *(const bf16x8*)(g);
        rv1 = *(const bf16x8*)(g + 32);
      }
    }
  }

  int c = 0, it = 0;
  for (int t = blockIdx.x; t < ntiles; t += gridDim.x, ++it) {
    const int base = t * 64;
    const int np = min(64, N - base);
    __syncthreads();
    if (it > 0) do_gemm2(c ^ 1);

    *(bf16x8*)(void*)&Xb[c][sp * LDP + sd0] = rv0;
    *(bf16x8*)(void*)&Xb[c][sp * LDP + sd0 + 32] = rv1;
#pragma unroll
    for (int k = 0; k < 8; k++) XTb[c][(sd0 + k) * LDP + sp] = (unsigned short)rv0[k];
#pragma unroll
    for (int k = 0; k < 8; k++) XTb[c][(sd0 + 32 + k) * LDP + sp] = (unsigned short)rv1[k];

    {
      int tn = t + gridDim.x;
      rv0 = bf16x8{0, 0, 0, 0, 0, 0, 0, 0};
      rv1 = bf16x8{0, 0, 0, 0, 0, 0, 0, 0};
      if (tn < ntiles) {
        int nbase = tn * 64;
        int nnp = min(64, N - nbase);
        if (sp < nnp) {
          const unsigned short* g = gsrc + (size_t)nbase * DM;
          rv0 = *(const bf16x8*)(g);
          rv1 = *(const bf16x8*)(g + 32);
        }
      }
    }
    __syncthreads();

    float Wv[4][4];
#pragma unroll
    for (int jt = 0; jt < 4; jt++)
#pragma unroll
      for (int r = 0; r < 4; r++) {
        int pl = 16 * w + quad * 4 + r;
        Wv[jt][r] = (pl < np)
            ? CU[(size_t)(base + pl) * CL + 16 * jt + col] : 0.0f;
      }

    float rr[4];
#pragma unroll
    for (int r = 0; r < 4; r++) {
      float rs = Wv[0][r] + Wv[1][r] + Wv[2][r] + Wv[3][r];
      rs = group16_sum(rs);
      int pl = 16 * w + quad * 4 + r;
      rr[r] = (pl < np) ? __builtin_amdgcn_rcpf(rs) : 0.0f;
    }

#pragma unroll
    for (int jt = 0; jt < 4; jt++) {
      float u0v = Wv[jt][0] * rr[0], u1v = Wv[jt][1] * rr[1];
      float u2v = Wv[jt][2] * rr[2], u3v = Wv[jt][3] * rr[3];
      uint2 pk = {cvtpk_bf16(u0v * u0v, u1v * u1v),
                  cvtpk_bf16(u2v * u2v, u3v * u3v)};
      *(uint2*)(void*)&umT[(16 * jt + col) * LDP + 16 * w + quad * 4] = pk;
    }
    c ^= 1;
  }
  if (it > 0) { __syncthreads(); do_gemm2(c ^ 1); }

  float* pbuf = partial + (size_t)blockIdx.x * PARTIAL_STRIDE;
  if (col == 0) {
    float4 dv = {Dden[0], Dden[1], Dden[2], Dden[3]};
    *(float4*)(void*)&pbuf[CL * DM + 16 * w + quad * 4] = dv;
  }
#pragma unroll
  for (int dt = 0; dt < 4; dt++)
#pragma unroll
    for (int r = 0; r < 4; r++)
      pbuf[(size_t)(16 * w + quad * 4 + r) * DM + dt * 16 + col] = D2[dt][r];
}

// Fused iteration k (k=0..24): blocks 0-63 reduce partials -> Cnew (+diff vs
// Cold when k>0, convergence tail by last ticket), all blocks spin on rdone
// (target 64*(k+1), monotonic), then run the R9 pass with CU=Cnew.
// Co-residency is guaranteed (grid<=768, 3 blocks/CU) so reducers always run.
__global__ __launch_bounds__(256, 3)
void fcm_iter(const unsigned short* __restrict__ xbf, const float* __restrict__ x2,
              float* __restrict__ Cnew, const float* __restrict__ Cold,
              float* __restrict__ partial, float* __restrict__ out,
              float* __restrict__ diffac, int* __restrict__ done,
              int* __restrict__ ticket, int* __restrict__ rdone,
              int k, int N, int ntiles, int nb) {
  if (*done) return;
  __shared__ __align__(16) unsigned short Xb[2][64 * LDP];
  __shared__ __align__(16) unsigned short XTb[2][64 * LDP];
  __shared__ __align__(16) unsigned short umT[64 * LDP];
  __shared__ __align__(16) float x2s[2][64];
  __shared__ int s_lastflag;
  __shared__ float s_sdiff;

  const int tid  = threadIdx.x;
  const int w    = __builtin_amdgcn_readfirstlane(tid >> 6);
  const int col  = tid & 15;
  const int quad = (tid >> 4) & 3;

  const int sp  = tid & 63;
  const int sd0 = (tid >> 6) * 8;
  const unsigned short* gsrc = xbf + (size_t)sp * DM + sd0;

  // ---- tile-0 prefetch issued BEFORE the reduce/wait (overlaps R latency) ----
  bf16x8 rv0 = {0, 0, 0, 0, 0, 0, 0, 0};
  bf16x8 rv1 = {0, 0, 0, 0, 0, 0, 0, 0};
  float rx2 = 0.0f;
  {
    int t0 = blockIdx.x;
    if (t0 < ntiles) {
      int base = t0 * 64;
      int np = min(64, N - base);
      if (sp < np) {
        const unsigned short* g = gsrc + (size_t)base * DM;
        rv0 = *(const bf16x8*)(g);
        rv1 = *(const bf16x8*)(g + 32);
      }
      if (tid < 64 && base + tid < N) rx2 = x2[base + tid];
    }
  }

  // ---- Phase R: blocks 0-63 each reduce one row j ----
  if (blockIdx.x < 64) {
    const int j = blockIdx.x;
    float* red  = (float*)&Xb[0][0];       // 256 floats (alias, pre-staging)
    float* sden = red + 256;               // 256 floats
    const int d = tid & 63;
    const int slice = tid >> 6;
    float s = 0.0f;
    for (int b = slice; b < nb; b += 4)
      s += partial[(size_t)b * PARTIAL_STRIDE + j * DM + d];
    red[slice * 64 + d] = s;
    float dv = 0.0f;
    for (int b = tid; b < nb; b += 256)
      dv += partial[(size_t)b * PARTIAL_STRIDE + CL * DM + j];
    sden[tid] = dv;
    __syncthreads();
    if (tid < 128) sden[tid] += sden[tid + 128];
    __syncthreads();
    if (tid < 64) sden[tid] += sden[tid + 64];
    __syncthreads();
    if (tid < 64) {
      float denj = wave_sum(sden[tid]);
      float cs = red[tid] + red[64 + tid] + red[128 + tid] + red[192 + tid];
      float cval = cs / denj;
      Cnew[j * DM + tid] = cval;
      if (k > 0) {
        float df = cval - Cold[j * DM + tid];
        float tot = wave_sum(df * df);
        if (tid == 0) atomicAdd(diffac, tot);
      }
    }
    __threadfence();
    if (k > 0) {
      if (tid == 0) s_lastflag = (atomicAdd(ticket, 1) == CL - 1);
      __syncthreads();
      if (s_lastflag) {
        if (tid == 0) s_sdiff = atomicAdd(diffac, 0.0f);
        __syncthreads();
        if (s_sdiff < 1e-16f) {            // diff < 1e-8  <=>  diff^2 < 1e-16
          for (int i = tid; i < CL * DM; i += 256) out[i] = Cold[i];
          if (tid == 0) *done = 1;
        }
        if (tid == 0) { *diffac = 0.0f; *ticket = 0; }
        __threadfence();
      }
    }
    __syncthreads();                       // LDS alias reads done before staging
    if (tid == 0) { __threadfence(); atomicAdd(rdone, 1); }
  }

  // ---- wait for all 64 rows of Cnew (monotonic counter; always reached) ----
  if (tid == 0) {
    while (__hip_atomic_load(rdone, __ATOMIC_RELAXED,
                             __HIP_MEMORY_SCOPE_AGENT) < 64 * (k + 1))
      __builtin_amdgcn_s_sleep(8);
  }
  __syncthreads();
  __threadfence();                         // acquire: see Cnew/done from other XCDs
  if (__hip_atomic_load(done, __ATOMIC_RELAXED, __HIP_MEMORY_SCOPE_AGENT)) return;

  // ---- Phase P: R9 pipelined pass with CU = Cnew ----
  bf16x8 cf0[4], cf1[4];
  float c2v[4];
#pragma unroll
  for (int jt = 0; jt < 4; jt++) {
    const float* crow = Cnew + (size_t)(16 * jt + col) * DM;
    float4 ca = *(const float4*)(crow + quad * 8);
    float4 cb = *(const float4*)(crow + quad * 8 + 4);
    float4 cc = *(const float4*)(crow + 32 + quad * 8);
    float4 cd = *(const float4*)(crow + 32 + quad * 8 + 4);
    float cp = ca.x*ca.x + ca.y*ca.y + ca.z*ca.z + ca.w*ca.w
             + cb.x*cb.x + cb.y*cb.y + cb.z*cb.z + cb.w*cb.w
             + cc.x*cc.x + cc.y*cc.y + cc.z*cc.z + cc.w*cc.w
             + cd.x*cd.x + cd.y*cd.y + cd.z*cd.z + cd.w*cd.w;
    cp += __shfl_xor(cp, 16, 64);
    cp += __shfl_xor(cp, 32, 64);
    c2v[jt] = cp;
    union { bf16x8 v; unsigned u[4]; } P0, P1;
    P0.u[0] = pkbf(ca.x, ca.y); P0.u[1] = pkbf(ca.z, ca.w);
    P0.u[2] = pkbf(cb.x, cb.y); P0.u[3] = pkbf(cb.z, cb.w);
    P1.u[0] = pkbf(cc.x, cc.y); P1.u[1] = pkbf(cc.z, cc.w);
    P1.u[2] = pkbf(cd.x, cd.y); P1.u[3] = pkbf(cd.z, cd.w);
    cf0[jt] = P0.v; cf1[jt] = P1.v;
  }

  union { bf16x8 v; unsigned u[4]; } ON;
  ON.u[0] = ON.u[1] = ON.u[2] = ON.u[3] = 0x3F803F80u;
  const bf16x8 onesf = ON.v;

  f32x4 D2[4];
#pragma unroll
  for (int dt = 0; dt < 4; dt++) D2[dt] = f32x4{0.f, 0.f, 0.f, 0.f};
  f32x4 Dden = f32x4{0.f, 0.f, 0.f, 0.f};

  auto do_gemm2 = [&](int cb) {
#pragma unroll
    for (int pb = 0; pb < 2; pb++) {
      bf16x8 au = *(const bf16x8*)(const void*)&umT[(16 * w + col) * LDP + pb * 32 + quad * 8];
      Dden = __builtin_amdgcn_mfma_f32_16x16x32_bf16(au, onesf, Dden, 0, 0, 0);
#pragma unroll
      for (int dt = 0; dt < 4; dt++) {
        bf16x8 bx = *(const bf16x8*)(const void*)&XTb[cb][(dt * 16 + col) * LDP + pb * 32 + quad * 8];
        D2[dt] = __builtin_amdgcn_mfma_f32_16x16x32_bf16(au, bx, D2[dt], 0, 0, 0);
      }
    }
  };

  int c = 0, it = 0;
  for (int t = blockIdx.x; t < ntiles; t += gridDim.x, ++it) {
    const int base = t * 64;
    const int np = min(64, N - base);
    __syncthreads();                       // barA
    if (it > 0) do_gemm2(c ^ 1);

    *(bf16x8*)(void*)&Xb[c][sp * LDP + sd0] = rv0;
    *(bf16x8*)(void*)&Xb[c][sp * LDP + sd0 + 32] = rv1;
#pragma unroll
    for (int q = 0; q < 8; q++) XTb[c][(sd0 + q) * LDP + sp] = (unsigned short)rv0[q];
#pragma unroll
    for (int q = 0; q < 8; q++) XTb[c][(sd0 + 32 + q) * LDP + sp] = (unsigned short)rv1[q];
    if (tid < 64) x2s[c][tid] = rx2;

    {
      int tn = t + gridDim.x;
      rv0 = bf16x8{0, 0, 0, 0, 0, 0, 0, 0};
      rv1 = bf16x8{0, 0, 0, 0, 0, 0, 0, 0};
      rx2 = 0.0f;
      if (tn < ntiles) {
        int nbase = tn * 64;
        int nnp = min(64, N - nbase);
        if (sp < nnp) {
          const unsigned short* g = gsrc + (size_t)nbase * DM;
          rv0 = *(const bf16x8*)(g);
          rv1 = *(const bf16x8*)(g + 32);
        }
        if (tid < 64 && nbase + tid < N) rx2 = x2[nbase + tid];
      }
    }
    __syncthreads();                       // barB

    float Wv[4][4];
    {
      bf16x8 a0 = *(const bf16x8*)(const void*)&Xb[c][(16 * w + col) * LDP + quad * 8];
      bf16x8 a1 = *(const bf16x8*)(const void*)&Xb[c][(16 * w + col) * LDP + 32 + quad * 8];
      f32x4 x2p = *(const f32x4*)(const void*)&x2s[c][16 * w + quad * 4];
#pragma unroll
      for (int jt = 0; jt < 4; jt++) {
        f32x4 s = f32x4{0.f, 0.f, 0.f, 0.f};
        s = __builtin_amdgcn_mfma_f32_16x16x32_bf16(a0, cf0[jt], s, 0, 0, 0);
        s = __builtin_amdgcn_mfma_f32_16x16x32_bf16(a1, cf1[jt], s, 0, 0, 0);
#pragma unroll
        for (int r = 0; r < 4; r++) {
          float dist = fmaxf(fmaf(-2.0f, s[r], x2p[r] + c2v[jt]), 0.0f);
          Wv[jt][r] = __builtin_amdgcn_rcpf(dist);   // d^(-p/2), p=2
        }
      }
    }

    float rr[4];
#pragma unroll
    for (int r = 0; r < 4; r++) {
      float rs = Wv[0][r] + Wv[1][r] + Wv[2][r] + Wv[3][r];
      rs = group16_sum(rs);
      int pl = 16 * w + quad * 4 + r;
      rr[r] = (pl < np) ? __builtin_amdgcn_rcpf(rs) : 0.0f;
    }

#pragma unroll
    for (int jt = 0; jt < 4; jt++) {
      float u0v = Wv[jt][0] * rr[0], u1v = Wv[jt][1] * rr[1];
      float u2v = Wv[jt][2] * rr[2], u3v = Wv[jt][3] * rr[3];
      uint2 pk = {cvtpk_bf16(u0v * u0v, u1v * u1v),
                  cvtpk_bf16(u2v * u2v, u3v * u3v)};
      *(uint2*)(void*)&umT[(16 * jt + col) * LDP + 16 * w + quad * 4] = pk;
    }
    c ^= 1;
  }
  if (it > 0) { __syncthreads(); do_gemm2(c ^ 1); }

  float* pbuf = partial + (size_t)blockIdx.x * PARTIAL_STRIDE;
  if (col == 0) {
    float4 dv = {Dden[0], Dden[1], Dden[2], Dden[3]};
    *(float4*)(void*)&pbuf[CL * DM + 16 * w + quad * 4] = dv;
  }
#pragma unroll
  for (int dt = 0; dt < 4; dt++)
#pragma unroll
    for (int r = 0; r < 4; r++)
      pbuf[(size_t)(16 * w + quad * 4 + r) * DM + dt * 16 + col] = D2[dt][r];
}

// Tail reduce (iteration 25): unchanged proven 64x1024 structure.
__global__ __launch_bounds__(1024, 1)
void fcm_reduce(const float* __restrict__ partial, float* __restrict__ Cnew,
                const float* __restrict__ Cold, float* __restrict__ out,
                float* __restrict__ diffac, int* __restrict__ done,
                int* __restrict__ ticket, int compute_diff, int nb) {
  if (compute_diff && *done) return;
  __shared__ float sm[16 * 64];
  __shared__ float sden[1024];
  __shared__ int lastflag;
  __shared__ float sdiff;
  int j = blockIdx.x;
  int tid = threadIdx.x;
  int d = tid & 63;
  int slice = tid >> 6;
  float s = 0.0f;
  for (int b = slice; b < nb; b += 16)
    s += partial[(size_t)b * PARTIAL_STRIDE + j * DM + d];
  sm[slice * 64 + d] = s;
  float dv = 0.0f;
  for (int b = tid; b < nb; b += 1024)
    dv += partial[(size_t)b * PARTIAL_STRIDE + CL * DM + j];
  sden[tid] = dv;
  __syncthreads();
#pragma unroll
  for (int st = 8; st; st >>= 1) {
    if (slice < st) sm[slice * 64 + d] += sm[(slice + st) * 64 + d];
    __syncthreads();
  }
#pragma unroll
  for (int st = 512; st >= 64; st >>= 1) {
    if (tid < st) sden[tid] += sden[tid + st];
    __syncthreads();
  }
  if (tid < 64) {
    float denj = wave_sum(sden[tid]);
    float c = sm[tid] / denj;
    Cnew[j * DM + tid] = c;
    if (compute_diff) {
      float df = c - Cold[j * DM + tid];
      float tot = wave_sum(df * df);
      if (tid == 0) atomicAdd(diffac, tot);
    }
  }
  if (!compute_diff) return;
  __syncthreads();
  if (tid == 0) {
    __threadfence();
    int t = atomicAdd(ticket, 1);
    lastflag = (t == (int)gridDim.x - 1);
  }
  __syncthreads();
  if (!lastflag) return;
  if (tid == 0) sdiff = atomicAdd(diffac, 0.0f);
  __syncthreads();
  if (sdiff < 1e-16f) {                 // diff < 1e-8  <=>  diff^2 < 1e-16
    for (int i = tid; i < CL * DM; i += 1024) out[i] = Cold[i];
    if (tid == 0) *done = 1;
  }
  if (tid == 0) { *diffac = 0.0f; *ticket = 0; }
}

// If never converged, V = C_25.
__global__ void fcm_final(const float* __restrict__ Clast, float* __restrict__ out,
                          const int* __restrict__ done) {
  if (*done) return;
  int i = blockIdx.x * blockDim.x + threadIdx.x;
  if (i < CL * DM) out[i] = Clast[i];
}

extern "C" void kernel_launch(void* const* d_in, const int* in_sizes, int n_in,
                              void* d_out, int out_size, void* d_ws, size_t ws_size,
                              hipStream_t stream) {
  const float* data = (const float*)d_in[0];
  const float* u0   = (const float*)d_in[1];
  float* out = (float*)d_out;
  int N = in_sizes[0] / DM;            // 300000
  int ntiles = (N + 63) / 64;          // 4688

  float* ws = (float*)d_ws;
  size_t Noff = ((size_t)N + 15) & ~(size_t)15;
  float* x2 = ws;                                  // N fp32
  unsigned short* xbf = (unsigned short*)(ws + Noff);  // N*64 bf16 = N*32 float slots
  float* C0 = ws + Noff + (size_t)N * 32;
  float* C1 = C0 + CL * DM;
  float* diffac = C1 + CL * DM;
  int* done = (int*)(diffac + 1);
  int* ticket = (int*)(diffac + 2);
  int* rdone = (int*)(diffac + 3);
  float* partial = diffac + 16;

  size_t used = Noff + (size_t)N * 32 + 2 * CL * DM + 16;
  size_t avail = (ws_size / 4 > used) ? (ws_size / 4 - used) / PARTIAL_STRIDE : 0;
  int nb = (int)(avail < MAX_BLOCKS ? avail : MAX_BLOCKS);
  if (nb < 64) nb = 64;                // phase R needs 64 reducer blocks

  size_t nvec = (size_t)N * (DM / 4);
  hipLaunchKernelGGL(fcm_prep, dim3((unsigned)((nvec + 255) / 256)), dim3(256), 0,
                     stream, data, x2, xbf, diffac, done, ticket, rdone, N);
  hipLaunchKernelGGL(fcm_pass_init, dim3(nb), dim3(256), 0, stream,
                     xbf, u0, partial, N, ntiles);

  float* bufs[2] = {C0, C1};
  for (int k = 0; k < MAX_ITER; k++) {
    float* Cn = bufs[k & 1];
    float* Co = bufs[(k + 1) & 1];     // unused when k==0 (cd off)
    hipLaunchKernelGGL(fcm_iter, dim3(nb), dim3(256), 0, stream,
                       xbf, x2, Cn, Co, partial, out, diffac, done, ticket,
                       rdone, k, N, ntiles, nb);
  }
  // tail: reduce #25 (C25 = bufs[1], diff vs C24 = bufs[0]) + final
  hipLaunchKernelGGL(fcm_reduce, dim3(64), dim3(1024), 0, stream,
                     partial, bufs[1], bufs[0], out, diffac, done, ticket, 1, nb);
  hipLaunchKernelGGL(fcm_final, dim3(16), dim3(256), 0, stream,
                     bufs[1], out, done);
}

// Round 7
// 398.913 us; speedup vs baseline: 1.8907x; 1.8907x over previous
//
#include <hip/hip_runtime.h>

// Fuzzy c-means on MI355X. N=300000, D=64, c=64, m=2 (p=2), 25 updates + init.
// R4: MFMA rewrite (432us). R5: bf16 xbf copy (427us). R6: VALU cuts (401us).
// R7: coalesced prep, nb=768 (390us). R8: per-wave-points GEMM1 (388us).
// R9: pipelined pass = WIN, atomic reduce = LOSS. R10: R9 pass + R8 reduce
// (379us). R11: in-kernel fused reduce+spin = LOSS (754us; 64-block reduce
// starved + whole-GPU spin). Kernel-boundary sync is the cheap sync here.
// R12: R10 skeleton + occupancy 3->4 blocks/CU: Xb and x2s are SINGLE
// buffered (GEMM1 is not deferred; barA/barB already protect them -> only
// XTb needs dbuf for the deferred GEMM2). LDS 46.6->37.1KB, launch_bounds
// (256,4), grid 768->1024 (critical path 7->5 tiles/block, 16 waves/CU).

#define DM 64
#define CL 64
#define PARTIAL_STRIDE 4160      // 64*64 num + 64 den
#define MAX_ITER 25
#define MAX_BLOCKS 1024
#define LDP 72                   // padded row length (bf16) for Xb/XTb/umT

typedef __attribute__((ext_vector_type(8))) short bf16x8;   // MFMA A/B frag (4 VGPRs)
typedef __attribute__((ext_vector_type(4))) float f32x4;    // MFMA C/D frag

__device__ __forceinline__ unsigned f2bf1(float f) {        // fp32 -> bf16 (RNE)
  unsigned u = __builtin_bit_cast(unsigned, f);
  return (u + 0x7FFFu + ((u >> 16) & 1u)) >> 16;
}
__device__ __forceinline__ unsigned pkbf(float a, float b) {
  return f2bf1(a) | (f2bf1(b) << 16);
}
// HW packed fp32->2xbf16 (RNE), gfx950. %1 -> low half, %2 -> high half.
__device__ __forceinline__ unsigned cvtpk_bf16(float a, float b) {
  unsigned r;
  asm("v_cvt_pk_bf16_f32 %0, %1, %2" : "=v"(r) : "v"(a), "v"(b));
  return r;
}

// 64-lane sum: DPP row reduce + bcast, result broadcast via readlane 63.
__device__ __forceinline__ float wave_sum(float v) {
#define DPPADD(ctrl, rmask)                                                  \
  v += __builtin_bit_cast(float, __builtin_amdgcn_update_dpp(                \
           0, __builtin_bit_cast(int, v), ctrl, rmask, 0xf, false));
  DPPADD(0x111, 0xf)   // row_shr:1
  DPPADD(0x112, 0xf)   // row_shr:2
  DPPADD(0x114, 0xf)   // row_shr:4
  DPPADD(0x118, 0xf)   // row_shr:8
  DPPADD(0x142, 0xa)   // row_bcast:15
  DPPADD(0x143, 0xc)   // row_bcast:31
#undef DPPADD
  return __builtin_bit_cast(
      float, __builtin_amdgcn_readlane(__builtin_bit_cast(int, v), 63));
}

// all-lanes sum within each 16-lane group, pure VALU (DPP).
__device__ __forceinline__ float group16_sum(float v) {
#define DPPADD(ctrl)                                                         \
  v += __builtin_bit_cast(float, __builtin_amdgcn_update_dpp(                \
           0, __builtin_bit_cast(int, v), ctrl, 0xf, 0xf, false));
  DPPADD(0xB1)    // quad_perm [1,0,3,2]  (xor 1)
  DPPADD(0x4E)    // quad_perm [2,3,0,1]  (xor 2)
  DPPADD(0x141)   // row_half_mirror
  DPPADD(0x140)   // row_mirror
#undef DPPADD
  return v;
}

// Coalesced prep: one float4 per lane, 16 lanes = one data row.
// x2[i] = ||x_i||^2 via DPP 16-lane sum; bf16 copy via hw cvt_pk; flag reset.
__global__ __launch_bounds__(256)
void fcm_prep(const float* __restrict__ data, float* __restrict__ x2,
              unsigned short* __restrict__ xbf,
              float* __restrict__ diffac, int* __restrict__ done,
              int* __restrict__ ticket, int N) {
  size_t i = (size_t)blockIdx.x * blockDim.x + threadIdx.x;   // float4 index
  if (i == 0) { *diffac = 0.0f; *done = 0; *ticket = 0; }
  size_t nvec = (size_t)N * (DM / 4);
  if (i >= nvec) return;                 // rows are 16 vecs: groups all-in/all-out
  float4 v = ((const float4*)data)[i];
  float s = fmaf(v.x, v.x, fmaf(v.y, v.y, fmaf(v.z, v.z, v.w * v.w)));
  float rs = group16_sum(s);             // row sum across the 16-lane group
  if ((threadIdx.x & 15) == 0) x2[i >> 4] = rs;
  uint2 pk = {cvtpk_bf16(v.x, v.y), cvtpk_bf16(v.z, v.w)};
  ((uint2*)xbf)[i] = pk;
}

// Fused pass, software-pipelined:
//   iter i: barA; [GEMM2(prev tile, XTb[c^1]+umT) || stage regs->Xb/XTb[c]];
//           issue loads(i+1); barB; GEMM1+softmax+umT(buf c).
// Xb/x2s are single-buffered: GEMM1(i) reads them between barB(i) and
// barA(i+1); stage(i+1) overwrites after barA(i+1). Only XTb is double
// (deferred GEMM2 reads it one iteration late); umT single (barA protects).
template <bool INIT>
__global__ __launch_bounds__(256, 4)
void fcm_pass(const unsigned short* __restrict__ xbf, const float* __restrict__ x2,
              const float* __restrict__ CU,   // INIT: u0[N][64]; else C[64][64]
              float* __restrict__ partial, const int* __restrict__ done,
              int N, int ntiles) {
  if (!INIT && *done) return;
  __shared__ __align__(16) unsigned short Xb[64 * LDP];      // X[p][d] bf16
  __shared__ __align__(16) unsigned short XTb[2][64 * LDP];  // X^T[d][p] bf16
  __shared__ __align__(16) unsigned short umT[64 * LDP];     // um^T[j][p] bf16
  __shared__ __align__(16) float x2s[64];

  const int tid  = threadIdx.x;
  const int w    = __builtin_amdgcn_readfirstlane(tid >> 6);  // wave id: POINT tile
  const int col  = tid & 15;
  const int quad = (tid >> 4) & 3;

  // ---- per-kernel prep: ALL 4 j-tiles' C rows -> c2v[jt] + bf16 B-frags ----
  bf16x8 cf0[4], cf1[4];
  float c2v[4];
  if (!INIT) {
#pragma unroll
    for (int jt = 0; jt < 4; jt++) {
      const float* crow = CU + (size_t)(16 * jt + col) * DM;
      float4 ca = *(const float4*)(crow + quad * 8);
      float4 cb = *(const float4*)(crow + quad * 8 + 4);
      float4 cc = *(const float4*)(crow + 32 + quad * 8);
      float4 cd = *(const float4*)(crow + 32 + quad * 8 + 4);
      float cp = ca.x*ca.x + ca.y*ca.y + ca.z*ca.z + ca.w*ca.w
               + cb.x*cb.x + cb.y*cb.y + cb.z*cb.z + cb.w*cb.w
               + cc.x*cc.x + cc.y*cc.y + cc.z*cc.z + cc.w*cc.w
               + cd.x*cd.x + cd.y*cd.y + cd.z*cd.z + cd.w*cd.w;
      cp += __shfl_xor(cp, 16, 64);
      cp += __shfl_xor(cp, 32, 64);
      c2v[jt] = cp;
      union { bf16x8 v; unsigned u[4]; } P0, P1;
      P0.u[0] = pkbf(ca.x, ca.y); P0.u[1] = pkbf(ca.z, ca.w);
      P0.u[2] = pkbf(cb.x, cb.y); P0.u[3] = pkbf(cb.z, cb.w);
      P1.u[0] = pkbf(cc.x, cc.y); P1.u[1] = pkbf(cc.z, cc.w);
      P1.u[2] = pkbf(cd.x, cd.y); P1.u[3] = pkbf(cd.z, cd.w);
      cf0[jt] = P0.v; cf1[jt] = P1.v;
    }
  }

  union { bf16x8 v; unsigned u[4]; } ON;
  ON.u[0] = ON.u[1] = ON.u[2] = ON.u[3] = 0x3F803F80u;   // bf16 1.0 x2
  const bf16x8 onesf = ON.v;

  f32x4 D2[4];
#pragma unroll
  for (int dt = 0; dt < 4; dt++) D2[dt] = f32x4{0.f, 0.f, 0.f, 0.f};
  f32x4 Dden = f32x4{0.f, 0.f, 0.f, 0.f};

  const int sp  = tid & 63;
  const int sd0 = (tid >> 6) * 8;                         // 0/8/16/24 by wave
  const unsigned short* gsrc = xbf + (size_t)sp * DM + sd0;

  // deferred GEMM2 over buffer cb (reads umT + XTb[cb], accumulates D2/Dden)
  auto do_gemm2 = [&](int cb) {
#pragma unroll
    for (int pb = 0; pb < 2; pb++) {
      bf16x8 au = *(const bf16x8*)(const void*)&umT[(16 * w + col) * LDP + pb * 32 + quad * 8];
      Dden = __builtin_amdgcn_mfma_f32_16x16x32_bf16(au, onesf, Dden, 0, 0, 0);
#pragma unroll
      for (int dt = 0; dt < 4; dt++) {
        bf16x8 bx = *(const bf16x8*)(const void*)&XTb[cb][(dt * 16 + col) * LDP + pb * 32 + quad * 8];
        D2[dt] = __builtin_amdgcn_mfma_f32_16x16x32_bf16(au, bx, D2[dt], 0, 0, 0);
      }
    }
  };

  // ---- prologue prefetch: tile #0 for this block ----
  bf16x8 rv0 = {0, 0, 0, 0, 0, 0, 0, 0};
  bf16x8 rv1 = {0, 0, 0, 0, 0, 0, 0, 0};
  float rx2 = 0.0f;
  {
    int t0 = blockIdx.x;
    if (t0 < ntiles) {
      int base = t0 * 64;
      int np = min(64, N - base);
      if (sp < np) {
        const unsigned short* g = gsrc + (size_t)base * DM;
        rv0 = *(const bf16x8*)(g);
        rv1 = *(const bf16x8*)(g + 32);
      }
      if (tid < 64 && base + tid < N) rx2 = x2[base + tid];
    }
  }

  int c = 0;
  int it = 0;
  for (int t = blockIdx.x; t < ntiles; t += gridDim.x, ++it) {
    const int base = t * 64;
    const int np = min(64, N - base);
    __syncthreads();                       // barA: prev compute done everywhere

    if (it > 0) do_gemm2(c ^ 1);           // finish previous tile (other XTb buf)

    // ---- stage prefetched regs -> Xb (single) + XTb[c] ----
    *(bf16x8*)(void*)&Xb[sp * LDP + sd0] = rv0;
    *(bf16x8*)(void*)&Xb[sp * LDP + sd0 + 32] = rv1;
#pragma unroll
    for (int k = 0; k < 8; k++) XTb[c][(sd0 + k) * LDP + sp] = (unsigned short)rv0[k];
#pragma unroll
    for (int k = 0; k < 8; k++) XTb[c][(sd0 + 32 + k) * LDP + sp] = (unsigned short)rv1[k];
    if (tid < 64) x2s[tid] = rx2;

    // ---- issue next tile's global loads (consumed next iteration) ----
    {
      int tn = t + gridDim.x;
      rv0 = bf16x8{0, 0, 0, 0, 0, 0, 0, 0};
      rv1 = bf16x8{0, 0, 0, 0, 0, 0, 0, 0};
      rx2 = 0.0f;
      if (tn < ntiles) {
        int nbase = tn * 64;
        int nnp = min(64, N - nbase);
        if (sp < nnp) {
          const unsigned short* g = gsrc + (size_t)nbase * DM;
          rv0 = *(const bf16x8*)(g);
          rv1 = *(const bf16x8*)(g + 32);
        }
        if (tid < 64 && nbase + tid < N) rx2 = x2[nbase + tid];
      }
    }
    __syncthreads();                       // barB: stage done, umT free

    // ---- W[jt][r] for p = 16w+quad*4+r, j = 16jt+col ----
    float Wv[4][4];
    if (INIT) {
#pragma unroll
      for (int jt = 0; jt < 4; jt++)
#pragma unroll
        for (int r = 0; r < 4; r++) {
          int pl = 16 * w + quad * 4 + r;
          Wv[jt][r] = (pl < np)
              ? CU[(size_t)(base + pl) * CL + 16 * jt + col] : 0.0f;
        }
    } else {
      bf16x8 a0 = *(const bf16x8*)(const void*)&Xb[(16 * w + col) * LDP + quad * 8];
      bf16x8 a1 = *(const bf16x8*)(const void*)&Xb[(16 * w + col) * LDP + 32 + quad * 8];
      f32x4 x2p = *(const f32x4*)(const void*)&x2s[16 * w + quad * 4];
#pragma unroll
      for (int jt = 0; jt < 4; jt++) {
        f32x4 s = f32x4{0.f, 0.f, 0.f, 0.f};
        s = __builtin_amdgcn_mfma_f32_16x16x32_bf16(a0, cf0[jt], s, 0, 0, 0);
        s = __builtin_amdgcn_mfma_f32_16x16x32_bf16(a1, cf1[jt], s, 0, 0, 0);
#pragma unroll
        for (int r = 0; r < 4; r++) {
          float dist = fmaxf(fmaf(-2.0f, s[r], x2p[r] + c2v[jt]), 0.0f);
          Wv[jt][r] = __builtin_amdgcn_rcpf(dist);   // d^(-p/2), p=2
        }
      }
    }

    // ---- rowsum in-register: in-lane over jt, DPP over col (bcast in group) ----
    float rr[4];
#pragma unroll
    for (int r = 0; r < 4; r++) {
      float rs = Wv[0][r] + Wv[1][r] + Wv[2][r] + Wv[3][r];
      rs = group16_sum(rs);
      int pl = 16 * w + quad * 4 + r;
      rr[r] = (pl < np) ? __builtin_amdgcn_rcpf(rs) : 0.0f;
    }

    // ---- um = (W * rr)^2 -> bf16 umT write (hw cvt_pk) ----
#pragma unroll
    for (int jt = 0; jt < 4; jt++) {
      float u0v = Wv[jt][0] * rr[0], u1v = Wv[jt][1] * rr[1];
      float u2v = Wv[jt][2] * rr[2], u3v = Wv[jt][3] * rr[3];
      uint2 pk = {cvtpk_bf16(u0v * u0v, u1v * u1v),
                  cvtpk_bf16(u2v * u2v, u3v * u3v)};
      *(uint2*)(void*)&umT[(16 * jt + col) * LDP + 16 * w + quad * 4] = pk;
    }
    c ^= 1;
  }

  // ---- drain: last tile's GEMM2 ----
  if (it > 0) {
    __syncthreads();
    do_gemm2(c ^ 1);
  }

  // ---- epilogue: write per-block partial (den from MFMA, col-duplicated) ----
  float* pbuf = partial + (size_t)blockIdx.x * PARTIAL_STRIDE;
  if (col == 0) {
    float4 dv = {Dden[0], Dden[1], Dden[2], Dden[3]};
    *(float4*)(void*)&pbuf[CL * DM + 16 * w + quad * 4] = dv;
  }
#pragma unroll
  for (int dt = 0; dt < 4; dt++)
#pragma unroll
    for (int r = 0; r < 4; r++)
      pbuf[(size_t)(16 * w + quad * 4 + r) * DM + dt * 16 + col] = D2[dt][r];
}

// Sum partials -> C_new; Frobenius diff; last block (ticket) does convergence
// check. R8-proven structure: 64 blocks x 1024 threads (16 waves/CU -> MLP).
__global__ __launch_bounds__(1024, 1)
void fcm_reduce(const float* __restrict__ partial, float* __restrict__ Cnew,
                const float* __restrict__ Cold, float* __restrict__ out,
                float* __restrict__ diffac, int* __restrict__ done,
                int* __restrict__ ticket, int compute_diff, int nb) {
  if (compute_diff && *done) return;
  __shared__ float sm[16 * 64];
  __shared__ float sden[1024];
  __shared__ int lastflag;
  __shared__ float sdiff;
  int j = blockIdx.x;
  int tid = threadIdx.x;
  int d = tid & 63;
  int slice = tid >> 6;
  float s = 0.0f;
  for (int b = slice; b < nb; b += 16)
    s += partial[(size_t)b * PARTIAL_STRIDE + j * DM + d];
  sm[slice * 64 + d] = s;
  float dv = 0.0f;
  for (int b = tid; b < nb; b += 1024)
    dv += partial[(size_t)b * PARTIAL_STRIDE + CL * DM + j];
  sden[tid] = dv;
  __syncthreads();
#pragma unroll
  for (int st = 8; st; st >>= 1) {
    if (slice < st) sm[slice * 64 + d] += sm[(slice + st) * 64 + d];
    __syncthreads();
  }
#pragma unroll
  for (int st = 512; st >= 64; st >>= 1) {
    if (tid < st) sden[tid] += sden[tid + st];
    __syncthreads();
  }
  if (tid < 64) {
    float denj = wave_sum(sden[tid]);
    float c = sm[tid] / denj;
    Cnew[j * DM + tid] = c;
    if (compute_diff) {
      float df = c - Cold[j * DM + tid];
      float tot = wave_sum(df * df);
      if (tid == 0) atomicAdd(diffac, tot);
    }
  }
  if (!compute_diff) return;
  __syncthreads();
  if (tid == 0) {
    __threadfence();
    int t = atomicAdd(ticket, 1);
    lastflag = (t == (int)gridDim.x - 1);
  }
  __syncthreads();
  if (!lastflag) return;
  if (tid == 0) sdiff = atomicAdd(diffac, 0.0f);
  __syncthreads();
  if (sdiff < 1e-16f) {                 // diff < 1e-8  <=>  diff^2 < 1e-16
    for (int i = tid; i < CL * DM; i += 1024) out[i] = Cold[i];
    if (tid == 0) *done = 1;
  }
  if (tid == 0) { *diffac = 0.0f; *ticket = 0; }
}

// If never converged, V = C_25.
__global__ void fcm_final(const float* __restrict__ Clast, float* __restrict__ out,
                          const int* __restrict__ done) {
  if (*done) return;
  int i = blockIdx.x * blockDim.x + threadIdx.x;
  if (i < CL * DM) out[i] = Clast[i];
}

extern "C" void kernel_launch(void* const* d_in, const int* in_sizes, int n_in,
                              void* d_out, int out_size, void* d_ws, size_t ws_size,
                              hipStream_t stream) {
  const float* data = (const float*)d_in[0];
  const float* u0   = (const float*)d_in[1];
  float* out = (float*)d_out;
  int N = in_sizes[0] / DM;            // 300000
  int ntiles = (N + 63) / 64;          // 4688

  float* ws = (float*)d_ws;
  size_t Noff = ((size_t)N + 15) & ~(size_t)15;
  float* x2 = ws;                                  // N fp32
  unsigned short* xbf = (unsigned short*)(ws + Noff);  // N*64 bf16 = N*32 float slots
  float* C0 = ws + Noff + (size_t)N * 32;
  float* C1 = C0 + CL * DM;
  float* diffac = C1 + CL * DM;
  int* done = (int*)(diffac + 1);
  int* ticket = (int*)(diffac + 2);
  float* partial = diffac + 16;

  size_t used = Noff + (size_t)N * 32 + 2 * CL * DM + 16;
  size_t avail = (ws_size / 4 > used) ? (ws_size / 4 - used) / PARTIAL_STRIDE : 0;
  int nb = (int)(avail < MAX_BLOCKS ? avail : MAX_BLOCKS);
  if (nb < 1) nb = 1;

  size_t nvec = (size_t)N * (DM / 4);
  hipLaunchKernelGGL(fcm_prep, dim3((unsigned)((nvec + 255) / 256)), dim3(256), 0,
                     stream, data, x2, xbf, diffac, done, ticket, N);
  hipLaunchKernelGGL((fcm_pass<true>), dim3(nb), dim3(256), 0, stream,
                     xbf, x2, u0, partial, done, N, ntiles);
  hipLaunchKernelGGL(fcm_reduce, dim3(64), dim3(1024), 0, stream,
                     partial, C0, C1, out, diffac, done, ticket, 0, nb);

  float* bufs[2] = {C0, C1};
  for (int k = 0; k < MAX_ITER; k++) {
    float* Cc = bufs[k & 1];
    float* Cn = bufs[(k + 1) & 1];
    hipLaunchKernelGGL((fcm_pass<false>), dim3(nb), dim3(256), 0, stream,
                       xbf, x2, Cc, partial, done, N, ntiles);
    hipLaunchKernelGGL(fcm_reduce, dim3(64), dim3(1024), 0, stream,
                       partial, Cn, Cc, out, diffac, done, ticket, 1, nb);
  }
  hipLaunchKernelGGL(fcm_final, dim3(16), dim3(256), 0, stream,
                     bufs[1], out, done);
}

// Round 8
// 381.742 us; speedup vs baseline: 1.9758x; 1.0450x over previous
//
#include <hip/hip_runtime.h>

// Fuzzy c-means on MI355X. N=300000, D=64, c=64, m=2 (p=2), 25 updates + init.
// R4-R8: MFMA + bf16 + VALU cuts + per-wave-points GEMM1 (388us).
// R9/R10: pipelined pass + R8 reduce (379us). R11: in-kernel fusion LOSS.
// R12: grid 1024 LOSS (+20us: reduce reads +33%, pass LDS-bound so more
// blocks don't help -- per-CU LDS work is grid-invariant).
// R13: grid back to 768; GEMM2 k-split: wave (jh=w>>1, kh=w&1) does j-tiles
// {2jh,2jh+1} x half-k (p in [32kh,32kh+32)). Block GEMM2 LDS reads
// 40KB -> 24KB/tile (waves no longer all re-read full X^T). kh-halves
// combined once per kernel via LDS scratch aliased over XTb.

#define DM 64
#define CL 64
#define PARTIAL_STRIDE 4160      // 64*64 num + 64 den
#define MAX_ITER 25
#define MAX_BLOCKS 768
#define LDP 72                   // padded row length (bf16) for Xb/XTb/umT

typedef __attribute__((ext_vector_type(8))) short bf16x8;   // MFMA A/B frag (4 VGPRs)
typedef __attribute__((ext_vector_type(4))) float f32x4;    // MFMA C/D frag

__device__ __forceinline__ unsigned f2bf1(float f) {        // fp32 -> bf16 (RNE)
  unsigned u = __builtin_bit_cast(unsigned, f);
  return (u + 0x7FFFu + ((u >> 16) & 1u)) >> 16;
}
__device__ __forceinline__ unsigned pkbf(float a, float b) {
  return f2bf1(a) | (f2bf1(b) << 16);
}
// HW packed fp32->2xbf16 (RNE), gfx950. %1 -> low half, %2 -> high half.
__device__ __forceinline__ unsigned cvtpk_bf16(float a, float b) {
  unsigned r;
  asm("v_cvt_pk_bf16_f32 %0, %1, %2" : "=v"(r) : "v"(a), "v"(b));
  return r;
}

// 64-lane sum: DPP row reduce + bcast, result broadcast via readlane 63.
__device__ __forceinline__ float wave_sum(float v) {
#define DPPADD(ctrl, rmask)                                                  \
  v += __builtin_bit_cast(float, __builtin_amdgcn_update_dpp(                \
           0, __builtin_bit_cast(int, v), ctrl, rmask, 0xf, false));
  DPPADD(0x111, 0xf)   // row_shr:1
  DPPADD(0x112, 0xf)   // row_shr:2
  DPPADD(0x114, 0xf)   // row_shr:4
  DPPADD(0x118, 0xf)   // row_shr:8
  DPPADD(0x142, 0xa)   // row_bcast:15
  DPPADD(0x143, 0xc)   // row_bcast:31
#undef DPPADD
  return __builtin_bit_cast(
      float, __builtin_amdgcn_readlane(__builtin_bit_cast(int, v), 63));
}

// all-lanes sum within each 16-lane group, pure VALU (DPP).
__device__ __forceinline__ float group16_sum(float v) {
#define DPPADD(ctrl)                                                         \
  v += __builtin_bit_cast(float, __builtin_amdgcn_update_dpp(                \
           0, __builtin_bit_cast(int, v), ctrl, 0xf, 0xf, false));
  DPPADD(0xB1)    // quad_perm [1,0,3,2]  (xor 1)
  DPPADD(0x4E)    // quad_perm [2,3,0,1]  (xor 2)
  DPPADD(0x141)   // row_half_mirror
  DPPADD(0x140)   // row_mirror
#undef DPPADD
  return v;
}

// Coalesced prep: one float4 per lane, 16 lanes = one data row.
__global__ __launch_bounds__(256)
void fcm_prep(const float* __restrict__ data, float* __restrict__ x2,
              unsigned short* __restrict__ xbf,
              float* __restrict__ diffac, int* __restrict__ done,
              int* __restrict__ ticket, int N) {
  size_t i = (size_t)blockIdx.x * blockDim.x + threadIdx.x;   // float4 index
  if (i == 0) { *diffac = 0.0f; *done = 0; *ticket = 0; }
  size_t nvec = (size_t)N * (DM / 4);
  if (i >= nvec) return;                 // rows are 16 vecs: groups all-in/all-out
  float4 v = ((const float4*)data)[i];
  float s = fmaf(v.x, v.x, fmaf(v.y, v.y, fmaf(v.z, v.z, v.w * v.w)));
  float rs = group16_sum(s);             // row sum across the 16-lane group
  if ((threadIdx.x & 15) == 0) x2[i >> 4] = rs;
  uint2 pk = {cvtpk_bf16(v.x, v.y), cvtpk_bf16(v.z, v.w)};
  ((uint2*)xbf)[i] = pk;
}

// Fused pass, software-pipelined (barrier-synced: umT writes(i) -> barA(i+1)
// -> gemm2 reads(i); stage(i) and gemm2(i-1) share the barA..barB window but
// touch different buffers: Xb/XTb[c] vs XTb[c^1]+umT).
//   iter i: barA; [GEMM2(prev, XTb[c^1]) || stage regs->Xb/XTb[c]];
//           issue loads(i+1); barB; GEMM1+softmax+umT(buf c).
// GEMM2 k-split: wave (jh,kh) owns j-tiles {2jh,2jh+1} x p-half kh.
template <bool INIT>
__global__ __launch_bounds__(256, 3)
void fcm_pass(const unsigned short* __restrict__ xbf, const float* __restrict__ x2,
              const float* __restrict__ CU,   // INIT: u0[N][64]; else C[64][64]
              float* __restrict__ partial, const int* __restrict__ done,
              int N, int ntiles) {
  if (!INIT && *done) return;
  __shared__ __align__(16) unsigned short Xb[64 * LDP];      // X[p][d] bf16
  __shared__ __align__(16) unsigned short XTb[2][64 * LDP];  // X^T[d][p] bf16
  __shared__ __align__(16) unsigned short umT[64 * LDP];     // um^T[j][p] bf16
  __shared__ __align__(16) float x2s[64];

  const int tid  = threadIdx.x;
  const int w    = __builtin_amdgcn_readfirstlane(tid >> 6);  // wave id: POINT tile
  const int col  = tid & 15;
  const int quad = (tid >> 4) & 3;
  const int jh   = w >> 1;             // GEMM2: j-tile pair {2jh, 2jh+1}
  const int kh   = w & 1;              // GEMM2: p-half [32kh, 32kh+32)

  // ---- per-kernel prep: ALL 4 j-tiles' C rows -> c2v[jt] + bf16 B-frags ----
  bf16x8 cf0[4], cf1[4];
  float c2v[4];
  if (!INIT) {
#pragma unroll
    for (int jt = 0; jt < 4; jt++) {
      const float* crow = CU + (size_t)(16 * jt + col) * DM;
      float4 ca = *(const float4*)(crow + quad * 8);
      float4 cb = *(const float4*)(crow + quad * 8 + 4);
      float4 cc = *(const float4*)(crow + 32 + quad * 8);
      float4 cd = *(const float4*)(crow + 32 + quad * 8 + 4);
      float cp = ca.x*ca.x + ca.y*ca.y + ca.z*ca.z + ca.w*ca.w
               + cb.x*cb.x + cb.y*cb.y + cb.z*cb.z + cb.w*cb.w
               + cc.x*cc.x + cc.y*cc.y + cc.z*cc.z + cc.w*cc.w
               + cd.x*cd.x + cd.y*cd.y + cd.z*cd.z + cd.w*cd.w;
      cp += __shfl_xor(cp, 16, 64);
      cp += __shfl_xor(cp, 32, 64);
      c2v[jt] = cp;
      union { bf16x8 v; unsigned u[4]; } P0, P1;
      P0.u[0] = pkbf(ca.x, ca.y); P0.u[1] = pkbf(ca.z, ca.w);
      P0.u[2] = pkbf(cb.x, cb.y); P0.u[3] = pkbf(cb.z, cb.w);
      P1.u[0] = pkbf(cc.x, cc.y); P1.u[1] = pkbf(cc.z, cc.w);
      P1.u[2] = pkbf(cd.x, cd.y); P1.u[3] = pkbf(cd.z, cd.w);
      cf0[jt] = P0.v; cf1[jt] = P1.v;
    }
  }

  union { bf16x8 v; unsigned u[4]; } ON;
  ON.u[0] = ON.u[1] = ON.u[2] = ON.u[3] = 0x3F803F80u;   // bf16 1.0 x2
  const bf16x8 onesf = ON.v;

  f32x4 D2[2][4];                      // [jt2][dt], this wave's k-half partial
#pragma unroll
  for (int jt2 = 0; jt2 < 2; jt2++)
#pragma unroll
    for (int dt = 0; dt < 4; dt++) D2[jt2][dt] = f32x4{0.f, 0.f, 0.f, 0.f};
  f32x4 Dden[2] = {f32x4{0.f, 0.f, 0.f, 0.f}, f32x4{0.f, 0.f, 0.f, 0.f}};

  const int sp  = tid & 63;
  const int sd0 = (tid >> 6) * 8;                         // 0/8/16/24 by wave
  const unsigned short* gsrc = xbf + (size_t)sp * DM + sd0;

  // k-split GEMM2 over XTb[cb]+umT: 6 b128 reads/wave (was 10), 10 MFMA.
  auto do_gemm2 = [&](int cb) {
    const int kb = kh * 32;            // p-offset of this wave's k-half
    bf16x8 bx0 = *(const bf16x8*)(const void*)&XTb[cb][(0 * 16 + col) * LDP + kb + quad * 8];
    bf16x8 bx1 = *(const bf16x8*)(const void*)&XTb[cb][(1 * 16 + col) * LDP + kb + quad * 8];
    bf16x8 bx2 = *(const bf16x8*)(const void*)&XTb[cb][(2 * 16 + col) * LDP + kb + quad * 8];
    bf16x8 bx3 = *(const bf16x8*)(const void*)&XTb[cb][(3 * 16 + col) * LDP + kb + quad * 8];
#pragma unroll
    for (int jt2 = 0; jt2 < 2; jt2++) {
      bf16x8 au = *(const bf16x8*)(const void*)&umT[(16 * (2 * jh + jt2) + col) * LDP + kb + quad * 8];
      Dden[jt2] = __builtin_amdgcn_mfma_f32_16x16x32_bf16(au, onesf, Dden[jt2], 0, 0, 0);
      D2[jt2][0] = __builtin_amdgcn_mfma_f32_16x16x32_bf16(au, bx0, D2[jt2][0], 0, 0, 0);
      D2[jt2][1] = __builtin_amdgcn_mfma_f32_16x16x32_bf16(au, bx1, D2[jt2][1], 0, 0, 0);
      D2[jt2][2] = __builtin_amdgcn_mfma_f32_16x16x32_bf16(au, bx2, D2[jt2][2], 0, 0, 0);
      D2[jt2][3] = __builtin_amdgcn_mfma_f32_16x16x32_bf16(au, bx3, D2[jt2][3], 0, 0, 0);
    }
  };

  // ---- prologue prefetch: tile #0 for this block ----
  bf16x8 rv0 = {0, 0, 0, 0, 0, 0, 0, 0};
  bf16x8 rv1 = {0, 0, 0, 0, 0, 0, 0, 0};
  float rx2 = 0.0f;
  {
    int t0 = blockIdx.x;
    if (t0 < ntiles) {
      int base = t0 * 64;
      int np = min(64, N - base);
      if (sp < np) {
        const unsigned short* g = gsrc + (size_t)base * DM;
        rv0 = *(const bf16x8*)(g);
        rv1 = *(const bf16x8*)(g + 32);
      }
      if (tid < 64 && base + tid < N) rx2 = x2[base + tid];
    }
  }

  int c = 0;
  int it = 0;
  for (int t = blockIdx.x; t < ntiles; t += gridDim.x, ++it) {
    const int base = t * 64;
    const int np = min(64, N - base);
    __syncthreads();                       // barA: prev compute done everywhere

    if (it > 0) do_gemm2(c ^ 1);           // finish previous tile (other XTb buf)

    // ---- stage prefetched regs -> Xb (single) + XTb[c] ----
    *(bf16x8*)(void*)&Xb[sp * LDP + sd0] = rv0;
    *(bf16x8*)(void*)&Xb[sp * LDP + sd0 + 32] = rv1;
#pragma unroll
    for (int k = 0; k < 8; k++) XTb[c][(sd0 + k) * LDP + sp] = (unsigned short)rv0[k];
#pragma unroll
    for (int k = 0; k < 8; k++) XTb[c][(sd0 + 32 + k) * LDP + sp] = (unsigned short)rv1[k];
    if (tid < 64) x2s[tid] = rx2;

    // ---- issue next tile's global loads (consumed next iteration) ----
    {
      int tn = t + gridDim.x;
      rv0 = bf16x8{0, 0, 0, 0, 0, 0, 0, 0};
      rv1 = bf16x8{0, 0, 0, 0, 0, 0, 0, 0};
      rx2 = 0.0f;
      if (tn < ntiles) {
        int nbase = tn * 64;
        int nnp = min(64, N - nbase);
        if (sp < nnp) {
          const unsigned short* g = gsrc + (size_t)nbase * DM;
          rv0 = *(const bf16x8*)(g);
          rv1 = *(const bf16x8*)(g + 32);
        }
        if (tid < 64 && nbase + tid < N) rx2 = x2[nbase + tid];
      }
    }
    __syncthreads();                       // barB: stage done, umT free

    // ---- W[jt][r] for p = 16w+quad*4+r, j = 16jt+col ----
    float Wv[4][4];
    if (INIT) {
#pragma unroll
      for (int jt = 0; jt < 4; jt++)
#pragma unroll
        for (int r = 0; r < 4; r++) {
          int pl = 16 * w + quad * 4 + r;
          Wv[jt][r] = (pl < np)
              ? CU[(size_t)(base + pl) * CL + 16 * jt + col] : 0.0f;
        }
    } else {
      bf16x8 a0 = *(const bf16x8*)(const void*)&Xb[(16 * w + col) * LDP + quad * 8];
      bf16x8 a1 = *(const bf16x8*)(const void*)&Xb[(16 * w + col) * LDP + 32 + quad * 8];
      f32x4 x2p = *(const f32x4*)(const void*)&x2s[16 * w + quad * 4];
#pragma unroll
      for (int jt = 0; jt < 4; jt++) {
        f32x4 s = f32x4{0.f, 0.f, 0.f, 0.f};
        s = __builtin_amdgcn_mfma_f32_16x16x32_bf16(a0, cf0[jt], s, 0, 0, 0);
        s = __builtin_amdgcn_mfma_f32_16x16x32_bf16(a1, cf1[jt], s, 0, 0, 0);
#pragma unroll
        for (int r = 0; r < 4; r++) {
          float dist = fmaxf(fmaf(-2.0f, s[r], x2p[r] + c2v[jt]), 0.0f);
          Wv[jt][r] = __builtin_amdgcn_rcpf(dist);   // d^(-p/2), p=2
        }
      }
    }

    // ---- rowsum in-register: in-lane over jt, DPP over col (bcast in group) ----
    float rr[4];
#pragma unroll
    for (int r = 0; r < 4; r++) {
      float rs = Wv[0][r] + Wv[1][r] + Wv[2][r] + Wv[3][r];
      rs = group16_sum(rs);
      int pl = 16 * w + quad * 4 + r;
      rr[r] = (pl < np) ? __builtin_amdgcn_rcpf(rs) : 0.0f;
    }

    // ---- um = (W * rr)^2 -> bf16 umT write (hw cvt_pk) ----
#pragma unroll
    for (int jt = 0; jt < 4; jt++) {
      float u0v = Wv[jt][0] * rr[0], u1v = Wv[jt][1] * rr[1];
      float u2v = Wv[jt][2] * rr[2], u3v = Wv[jt][3] * rr[3];
      uint2 pk = {cvtpk_bf16(u0v * u0v, u1v * u1v),
                  cvtpk_bf16(u2v * u2v, u3v * u3v)};
      *(unsigned long long*)(void*)&umT[(16 * jt + col) * LDP + 16 * w + quad * 4] =
          (unsigned long long)pk.x | ((unsigned long long)pk.y << 32);
    }
    c ^= 1;
  }

  // ---- drain: last tile's GEMM2 ----
  if (it > 0) {
    __syncthreads();
    do_gemm2(c ^ 1);
  }

  // ---- combine k-halves (once per kernel): kh=1 -> LDS -> kh=0 adds ----
  __syncthreads();                       // all gemm2 LDS reads done (alias safe)
  float* cmb  = (float*)&XTb[0][0];      // 16KB scratch for D2 halves
  float* cmbd = (float*)&umT[0];         // 4KB scratch for Dden halves
  const int lane = tid & 63;
  if (kh == 1) {
#pragma unroll
    for (int jt2 = 0; jt2 < 2; jt2++) {
#pragma unroll
      for (int dt = 0; dt < 4; dt++)
        *(f32x4*)(void*)&cmb[((jh * 64 + lane) * 8 + jt2 * 4 + dt) * 4] = D2[jt2][dt];
      *(f32x4*)(void*)&cmbd[(jh * 64 + lane) * 8 + jt2 * 4] = Dden[jt2];
    }
  }
  __syncthreads();
  if (kh == 0) {
    float* pbuf = partial + (size_t)blockIdx.x * PARTIAL_STRIDE;
#pragma unroll
    for (int jt2 = 0; jt2 < 2; jt2++) {
      const int jt = 2 * jh + jt2;
#pragma unroll
      for (int dt = 0; dt < 4; dt++) {
        f32x4 o = *(const f32x4*)(const void*)&cmb[((jh * 64 + lane) * 8 + jt2 * 4 + dt) * 4];
        D2[jt2][dt] += o;
#pragma unroll
        for (int r = 0; r < 4; r++)
          pbuf[(size_t)(16 * jt + quad * 4 + r) * DM + dt * 16 + col] = D2[jt2][dt][r];
      }
      f32x4 od = *(const f32x4*)(const void*)&cmbd[(jh * 64 + lane) * 8 + jt2 * 4];
      Dden[jt2] += od;
      if (col == 0) {
        float4 dv = {Dden[jt2][0], Dden[jt2][1], Dden[jt2][2], Dden[jt2][3]};
        *(float4*)(void*)&pbuf[CL * DM + 16 * jt + quad * 4] = dv;
      }
    }
  }
}

// Sum partials -> C_new; Frobenius diff; last block (ticket) does convergence
// check. R8-proven structure: 64 blocks x 1024 threads (16 waves/CU -> MLP).
__global__ __launch_bounds__(1024, 1)
void fcm_reduce(const float* __restrict__ partial, float* __restrict__ Cnew,
                const float* __restrict__ Cold, float* __restrict__ out,
                float* __restrict__ diffac, int* __restrict__ done,
                int* __restrict__ ticket, int compute_diff, int nb) {
  if (compute_diff && *done) return;
  __shared__ float sm[16 * 64];
  __shared__ float sden[1024];
  __shared__ int lastflag;
  __shared__ float sdiff;
  int j = blockIdx.x;
  int tid = threadIdx.x;
  int d = tid & 63;
  int slice = tid >> 6;
  float s = 0.0f;
  for (int b = slice; b < nb; b += 16)
    s += partial[(size_t)b * PARTIAL_STRIDE + j * DM + d];
  sm[slice * 64 + d] = s;
  float dv = 0.0f;
  for (int b = tid; b < nb; b += 1024)
    dv += partial[(size_t)b * PARTIAL_STRIDE + CL * DM + j];
  sden[tid] = dv;
  __syncthreads();
#pragma unroll
  for (int st = 8; st; st >>= 1) {
    if (slice < st) sm[slice * 64 + d] += sm[(slice + st) * 64 + d];
    __syncthreads();
  }
#pragma unroll
  for (int st = 512; st >= 64; st >>= 1) {
    if (tid < st) sden[tid] += sden[tid + st];
    __syncthreads();
  }
  if (tid < 64) {
    float denj = wave_sum(sden[tid]);
    float c = sm[tid] / denj;
    Cnew[j * DM + tid] = c;
    if (compute_diff) {
      float df = c - Cold[j * DM + tid];
      float tot = wave_sum(df * df);
      if (tid == 0) atomicAdd(diffac, tot);
    }
  }
  if (!compute_diff) return;
  __syncthreads();
  if (tid == 0) {
    __threadfence();
    int t = atomicAdd(ticket, 1);
    lastflag = (t == (int)gridDim.x - 1);
  }
  __syncthreads();
  if (!lastflag) return;
  if (tid == 0) sdiff = atomicAdd(diffac, 0.0f);
  __syncthreads();
  if (sdiff < 1e-16f) {                 // diff < 1e-8  <=>  diff^2 < 1e-16
    for (int i = tid; i < CL * DM; i += 1024) out[i] = Cold[i];
    if (tid == 0) *done = 1;
  }
  if (tid == 0) { *diffac = 0.0f; *ticket = 0; }
}

// If never converged, V = C_25.
__global__ void fcm_final(const float* __restrict__ Clast, float* __restrict__ out,
                          const int* __restrict__ done) {
  if (*done) return;
  int i = blockIdx.x * blockDim.x + threadIdx.x;
  if (i < CL * DM) out[i] = Clast[i];
}

extern "C" void kernel_launch(void* const* d_in, const int* in_sizes, int n_in,
                              void* d_out, int out_size, void* d_ws, size_t ws_size,
                              hipStream_t stream) {
  const float* data = (const float*)d_in[0];
  const float* u0   = (const float*)d_in[1];
  float* out = (float*)d_out;
  int N = in_sizes[0] / DM;            // 300000
  int ntiles = (N + 63) / 64;          // 4688

  float* ws = (float*)d_ws;
  size_t Noff = ((size_t)N + 15) & ~(size_t)15;
  float* x2 = ws;                                  // N fp32
  unsigned short* xbf = (unsigned short*)(ws + Noff);  // N*64 bf16 = N*32 float slots
  float* C0 = ws + Noff + (size_t)N * 32;
  float* C1 = C0 + CL * DM;
  float* diffac = C1 + CL * DM;
  int* done = (int*)(diffac + 1);
  int* ticket = (int*)(diffac + 2);
  float* partial = diffac + 16;

  size_t used = Noff + (size_t)N * 32 + 2 * CL * DM + 16;
  size_t avail = (ws_size / 4 > used) ? (ws_size / 4 - used) / PARTIAL_STRIDE : 0;
  int nb = (int)(avail < MAX_BLOCKS ? avail : MAX_BLOCKS);
  if (nb < 1) nb = 1;

  size_t nvec = (size_t)N * (DM / 4);
  hipLaunchKernelGGL(fcm_prep, dim3((unsigned)((nvec + 255) / 256)), dim3(256), 0,
                     stream, data, x2, xbf, diffac, done, ticket, N);
  hipLaunchKernelGGL((fcm_pass<true>), dim3(nb), dim3(256), 0, stream,
                     xbf, x2, u0, partial, done, N, ntiles);
  hipLaunchKernelGGL(fcm_reduce, dim3(64), dim3(1024), 0, stream,
                     partial, C0, C1, out, diffac, done, ticket, 0, nb);

  float* bufs[2] = {C0, C1};
  for (int k = 0; k < MAX_ITER; k++) {
    float* Cc = bufs[k & 1];
    float* Cn = bufs[(k + 1) & 1];
    hipLaunchKernelGGL((fcm_pass<false>), dim3(nb), dim3(256), 0, stream,
                       xbf, x2, Cc, partial, done, N, ntiles);
    hipLaunchKernelGGL(fcm_reduce, dim3(64), dim3(1024), 0, stream,
                       partial, Cn, Cc, out, diffac, done, ticket, 1, nb);
  }
  hipLaunchKernelGGL(fcm_final, dim3(16), dim3(256), 0, stream,
                     bufs[1], out, done);
}